// Round 5
// baseline (65.791 us; speedup 1.0000x reference)
//
#include <hip/hip_runtime.h>

#define B 128
#define N 512
#define D 256
#define S 8

typedef float f32x4 __attribute__((ext_vector_type(4)));

// ---------------------------------------------------------------------------
// K1 (fused): grid (16, B), block 256 (4 waves -> 32 waves/CU, 100% occ cap).
//   role in [0,8):  edge chunk -> em[b,:] += sum_i edge[b,i,:]*ka[b,i]
//                   2 row-groups x 128 float4-cols per block
//   role in [8,16): node chunk -> kf[b,:] += sum_n node[b,n,:]*ka[b,n]
//                   4 row-groups x 64 float4-cols, LDS tree-reduce
//                   + out_att chunk (NT stores) (+ out_sp once)
// R3 lesson: compiler won't give ILP (VGPR stuck at 32) -> get MLP from TLP.
// ---------------------------------------------------------------------------
__global__ __launch_bounds__(256) void k1_fused(
    const float* __restrict__ node, const float* __restrict__ edge,
    const float* __restrict__ att, const float* __restrict__ spi,
    float* __restrict__ out_att, float* __restrict__ out_sp,
    float* __restrict__ kf, float* __restrict__ em) {
    const int b = blockIdx.y;
    const int role = blockIdx.x;
    const int tid = threadIdx.x;
    __shared__ float sps[S];
    __shared__ float kal[64];
    if (tid < S) sps[tid] = spi[b * S + tid];
    __syncthreads();

    if (role < 8) {
        // ---- edge reduction chunk: 64 rows x 512 cols ----
        const int i0 = role * 64;
        if (tid < 64) {
            const float4* a = reinterpret_cast<const float4*>(att + ((size_t)(b * N + i0 + tid)) * S);
            float4 a0 = a[0], a1 = a[1];
            kal[tid] = a0.x * sps[0] + a0.y * sps[1] + a0.z * sps[2] + a0.w * sps[3]
                     + a1.x * sps[4] + a1.y * sps[5] + a1.z * sps[6] + a1.w * sps[7];
        }
        __syncthreads();
        const int r = tid >> 7;          // row-group 0/1
        const int c = tid & 127;         // float4 column of N
        const float4* base = reinterpret_cast<const float4*>(edge + ((size_t)(b * N + i0)) * N)
                           + (size_t)r * (N / 4) + c;
        float4 acc = make_float4(0.f, 0.f, 0.f, 0.f);
        float4 v[8];
        for (int dr0 = 0; dr0 < 32; dr0 += 8) {
            #pragma unroll
            for (int u = 0; u < 8; ++u) v[u] = base[(size_t)(dr0 + u) * 2 * (N / 4)];
            #pragma unroll
            for (int u = 0; u < 8; ++u) {
                float k = kal[(dr0 + u) * 2 + r];
                acc.x += k * v[u].x; acc.y += k * v[u].y;
                acc.z += k * v[u].z; acc.w += k * v[u].w;
            }
        }
        float* dst = em + b * N + c * 4;
        unsafeAtomicAdd(dst + 0, acc.x);
        unsafeAtomicAdd(dst + 1, acc.y);
        unsafeAtomicAdd(dst + 2, acc.z);
        unsafeAtomicAdd(dst + 3, acc.w);
    } else {
        // ---- node reduction chunk: 64 rows x 256 cols (+ stack outputs) ----
        const int n0 = (role - 8) * 64;
        __shared__ float4 red[256];
        if (tid < 64) {
            const float4* a = reinterpret_cast<const float4*>(att + ((size_t)(b * N + n0 + tid)) * S);
            float4 a0 = a[0], a1 = a[1];
            kal[tid] = a0.x * sps[0] + a0.y * sps[1] + a0.z * sps[2] + a0.w * sps[3]
                     + a1.x * sps[4] + a1.y * sps[5] + a1.z * sps[6] + a1.w * sps[7];
            f32x4 o0 = {a0.x * (1.f - sps[0]), a0.y * (1.f - sps[1]),
                        a0.z * (1.f - sps[2]), a0.w * (1.f - sps[3])};
            f32x4 o1 = {a1.x * (1.f - sps[4]), a1.y * (1.f - sps[5]),
                        a1.z * (1.f - sps[6]), a1.w * (1.f - sps[7])};
            f32x4* oa = reinterpret_cast<f32x4*>(out_att + ((size_t)(b * N + n0 + tid)) * S);
            __builtin_nontemporal_store(o0, &oa[0]);
            __builtin_nontemporal_store(o1, &oa[1]);
        }
        if (role == 8 && tid < S) {
            float v = (tid < S - 1) ? sps[tid + 1] : 0.0f;
            if (tid == 0) v += sps[0];
            out_sp[b * S + tid] = v;
        }
        __syncthreads();
        const int r = tid >> 6;          // row-group 0..3
        const int c = tid & 63;          // float4 column of D
        const float4* base = reinterpret_cast<const float4*>(node + ((size_t)(b * N + n0)) * D)
                           + (size_t)r * (D / 4) + c;
        float4 acc = make_float4(0.f, 0.f, 0.f, 0.f);
        float4 v[8];
        for (int j0 = 0; j0 < 16; j0 += 8) {
            #pragma unroll
            for (int u = 0; u < 8; ++u) v[u] = base[(size_t)(j0 + u) * 4 * (D / 4)];
            #pragma unroll
            for (int u = 0; u < 8; ++u) {
                float k = kal[(j0 + u) * 4 + r];
                acc.x += k * v[u].x; acc.y += k * v[u].y;
                acc.z += k * v[u].z; acc.w += k * v[u].w;
            }
        }
        red[tid] = acc;
        __syncthreads();
        if (tid < 64) {
            float4 a0 = red[c], a1 = red[c + 64], a2 = red[c + 128], a3 = red[c + 192];
            float4 s = make_float4(a0.x + a1.x + a2.x + a3.x,
                                   a0.y + a1.y + a2.y + a3.y,
                                   a0.z + a1.z + a2.z + a3.z,
                                   a0.w + a1.w + a2.w + a3.w);
            float* dst = kf + b * D + c * 4;
            unsafeAtomicAdd(dst + 0, s.x);
            unsafeAtomicAdd(dst + 1, s.y);
            unsafeAtomicAdd(dst + 2, s.z);
            unsafeAtomicAdd(dst + 3, s.w);
        }
    }
}

// ---------------------------------------------------------------------------
// K2: q[b,d] = bias[d] + sum_k W[d,k] * kf[b,k]   (grid B, block D)
// ---------------------------------------------------------------------------
__global__ void kC_q(const float* __restrict__ Wm,
                     const float* __restrict__ bias,
                     const float* __restrict__ kf,
                     float* __restrict__ q) {
    const int b = blockIdx.x;
    const int d = threadIdx.x;
    __shared__ float kfl[D];
    kfl[d] = kf[b * D + d];
    __syncthreads();
    float acc = bias[d];
    const float4* wrow = reinterpret_cast<const float4*>(Wm + (size_t)d * D);
    const float4* kf4 = reinterpret_cast<const float4*>(kfl);
    float4 w[8];
    for (int k0 = 0; k0 < D / 4; k0 += 8) {
        #pragma unroll
        for (int u = 0; u < 8; ++u) w[u] = wrow[k0 + u];
        #pragma unroll
        for (int u = 0; u < 8; ++u) {
            float4 f = kf4[k0 + u];
            acc += w[u].x * f.x + w[u].y * f.y + w[u].z * f.z + w[u].w * f.w;
        }
    }
    q[b * D + d] = acc;
}

// ---------------------------------------------------------------------------
// K3: out_vm[b,n] = vm[b,n] + em[b,n] * dot(node[b,n,:], q[b,:])
// one wave per row (64 lanes x float4 = 256 floats); 32 rows per block.
// ---------------------------------------------------------------------------
__global__ void kD_logits(const float* __restrict__ node,
                          const float* __restrict__ em,
                          const float* __restrict__ q,
                          const float* __restrict__ vm,
                          float* __restrict__ out_vm) {
    const int row0 = blockIdx.x * 32;
    const int b = row0 / N;
    const int tid = threadIdx.x;
    const int wave = tid >> 6;
    const int lane = tid & 63;
    __shared__ float ql[D];
    if (tid < D) ql[tid] = q[b * D + tid];
    __syncthreads();
    const float4 q4 = reinterpret_cast<const float4*>(ql)[lane];
    const int wr0 = row0 + wave * 8;
    float emv = 0.f, vmv = 0.f;
    if (lane < 8) {
        emv = em[wr0 + lane];
        vmv = vm[wr0 + lane];
    }
    float4 v[8];
    #pragma unroll
    for (int r = 0; r < 8; ++r)
        v[r] = reinterpret_cast<const float4*>(node + (size_t)(wr0 + r) * D)[lane];
    float myS = 0.f;
    #pragma unroll
    for (int r = 0; r < 8; ++r) {
        float s = v[r].x * q4.x + v[r].y * q4.y + v[r].z * q4.z + v[r].w * q4.w;
        #pragma unroll
        for (int off = 32; off; off >>= 1) s += __shfl_xor(s, off);
        if (lane == r) myS = s;
    }
    if (lane < 8) {
        out_vm[wr0 + lane] = vmv + emv * myS;
    }
}

extern "C" void kernel_launch(void* const* d_in, const int* in_sizes, int n_in,
                              void* d_out, int out_size, void* d_ws, size_t ws_size,
                              hipStream_t stream) {
    const float* node = (const float*)d_in[0];
    // d_in[1] = query : unused by the reference computation
    const float* edge = (const float*)d_in[2];
    const float* att  = (const float*)d_in[3];
    const float* sp   = (const float*)d_in[4];
    const float* vm   = (const float*)d_in[5];
    const float* Wm   = (const float*)d_in[6];
    const float* bias = (const float*)d_in[7];

    float* out_att = (float*)d_out;                    // B*N*S
    float* out_sp  = out_att + (size_t)B * N * S;      // B*S
    float* out_vm  = out_sp + (size_t)B * S;           // B*N

    float* ws = (float*)d_ws;
    float* kf = ws;                          // B*D (atomic-accumulated -> zero)
    float* em = kf + (size_t)B * D;          // B*N (atomic-accumulated -> zero)
    float* q  = em + (size_t)B * N;          // B*D

    (void)hipMemsetAsync(kf, 0, (size_t)(B * D + B * N) * sizeof(float), stream);

    k1_fused<<<dim3(16, B), 256, 0, stream>>>(node, edge, att, sp,
                                              out_att, out_sp, kf, em);
    kC_q<<<B, D, 0, stream>>>(Wm, bias, kf, q);
    kD_logits<<<(B * N) / 32, 256, 0, stream>>>(node, em, q, vm, out_vm);
}